// Round 5
// baseline (123.947 us; speedup 1.0000x reference)
//
#include <hip/hip_runtime.h>
#include <math.h>

// Problem constants (reference: B=4, N=8192, PIXEL_DIM=3).
#define BB   4
#define NN   8192
#define BN   (BB * NN)
#define TPB  256

// Schraudolph exp2: p = bitcast(int(s*2^23 + B)), B = (127-c)*2^23, c=0.0355
// balances max rel err to ~+/-3.5%; the systematic part cancels in softmax.
#define EXP2_B 1.06505542e9f
// q pre-scale: log2(e)/sqrt(3) * 2^23 (score scale + bit-trick scale folded).
#define QSCALE (8388608.0f * 1.4426950408889634f / 1.7320508075688772f)

// ---------------------------------------------------------------------------
// Fused QKV + split-K attention partials.
// qkv row mapping (reference view(B,N,3,-1)[...,i], d==3):
//   q_j = row 3j (0,3,6), k_j = 3j+1 (1,4,7), v_j = 3j+2 (2,5,8).
// Per (key,query) pair: 3 FMA (dot seeded with EXP2_B) + 1 cvt + 4 FMA/add
// = 8 VALU ops = 0.25 SIMD-cyc/pair.
// R4 post-mortem: QQ=4 exactly co-saturates the LDS pipe (18 LDS-cyc vs 72
// VALU-cyc per j-iter, both 133M j-iter/s/CU) -> QQ=8 halves LDS demand;
// NSEG=64 keeps 1024 blocks = 4 blocks/CU = 16 waves/CU for latency hiding.
// ---------------------------------------------------------------------------
template <int NSEG_T, int QQ_T>
__global__ __launch_bounds__(TPB) void attn_fused_kernel(const float* __restrict__ x,
                                                         const float* __restrict__ W,
                                                         const float* __restrict__ bias,
                                                         float4* __restrict__ part) {
    constexpr int SEGK_T  = NN / NSEG_T;       // 128 at NSEG=64
    constexpr int QTILE_T = TPB * QQ_T;        // 2048 at QQ=8
    __shared__ float4 ldsa[SEGK_T];            // k0,k1,k2,v0
    __shared__ float2 ldsc[SEGK_T];            // v1,v2

    const int seg = blockIdx.x;
    const int qt  = blockIdx.y;
    const int b   = blockIdx.z;
    const int t   = threadIdx.x;

    // Uniform weights -> registers (scalar-promoted).
    float Wr[9][3], br[9];
#pragma unroll
    for (int c = 0; c < 9; ++c) {
        Wr[c][0] = W[c * 3 + 0];
        Wr[c][1] = W[c * 3 + 1];
        Wr[c][2] = W[c * 3 + 2];
        br[c] = bias[c];
    }

    // Stage key segment (compute k,v from x on the fly). If the segment is
    // smaller than the block, split each key's 6 outputs across two threads.
    if (SEGK_T >= TPB) {
        for (int i = t; i < SEGK_T; i += TPB) {
            const float* xk = x + (size_t)(b * NN + seg * SEGK_T + i) * 3;
            float x0 = xk[0], x1 = xk[1], x2 = xk[2];
            float k0 = fmaf(x0, Wr[1][0], fmaf(x1, Wr[1][1], fmaf(x2, Wr[1][2], br[1])));
            float k1 = fmaf(x0, Wr[4][0], fmaf(x1, Wr[4][1], fmaf(x2, Wr[4][2], br[4])));
            float k2 = fmaf(x0, Wr[7][0], fmaf(x1, Wr[7][1], fmaf(x2, Wr[7][2], br[7])));
            float v0 = fmaf(x0, Wr[2][0], fmaf(x1, Wr[2][1], fmaf(x2, Wr[2][2], br[2])));
            float v1 = fmaf(x0, Wr[5][0], fmaf(x1, Wr[5][1], fmaf(x2, Wr[5][2], br[5])));
            float v2 = fmaf(x0, Wr[8][0], fmaf(x1, Wr[8][1], fmaf(x2, Wr[8][2], br[8])));
            ldsa[i] = make_float4(k0, k1, k2, v0);
            ldsc[i] = make_float2(v1, v2);
        }
    } else {
        int i = t & (SEGK_T - 1);
        const float* xk = x + (size_t)(b * NN + seg * SEGK_T + i) * 3;
        float x0 = xk[0], x1 = xk[1], x2 = xk[2];
        if (t < SEGK_T) {
            float k0 = fmaf(x0, Wr[1][0], fmaf(x1, Wr[1][1], fmaf(x2, Wr[1][2], br[1])));
            float k1 = fmaf(x0, Wr[4][0], fmaf(x1, Wr[4][1], fmaf(x2, Wr[4][2], br[4])));
            float k2 = fmaf(x0, Wr[7][0], fmaf(x1, Wr[7][1], fmaf(x2, Wr[7][2], br[7])));
            float v0 = fmaf(x0, Wr[2][0], fmaf(x1, Wr[2][1], fmaf(x2, Wr[2][2], br[2])));
            ldsa[i] = make_float4(k0, k1, k2, v0);
        } else {
            float v1 = fmaf(x0, Wr[5][0], fmaf(x1, Wr[5][1], fmaf(x2, Wr[5][2], br[5])));
            float v2 = fmaf(x0, Wr[8][0], fmaf(x1, Wr[8][1], fmaf(x2, Wr[8][2], br[8])));
            ldsc[i] = make_float2(v1, v2);
        }
    }

    // Per-thread queries, pre-scaled into Schraudolph domain.
    const int qbase = b * NN + qt * QTILE_T + t;
    float qx[QQ_T], qy[QQ_T], qz[QQ_T];
#pragma unroll
    for (int u = 0; u < QQ_T; ++u) {
        const float* xq = x + (size_t)(qbase + TPB * u) * 3;
        float x0 = xq[0], x1 = xq[1], x2 = xq[2];
        qx[u] = QSCALE * fmaf(x0, Wr[0][0], fmaf(x1, Wr[0][1], fmaf(x2, Wr[0][2], br[0])));
        qy[u] = QSCALE * fmaf(x0, Wr[3][0], fmaf(x1, Wr[3][1], fmaf(x2, Wr[3][2], br[3])));
        qz[u] = QSCALE * fmaf(x0, Wr[6][0], fmaf(x1, Wr[6][1], fmaf(x2, Wr[6][2], br[6])));
    }

    __syncthreads();

    float l[QQ_T], o0[QQ_T], o1[QQ_T], o2[QQ_T];
#pragma unroll
    for (int u = 0; u < QQ_T; ++u) { l[u] = 0.f; o0[u] = 0.f; o1[u] = 0.f; o2[u] = 0.f; }

#pragma unroll 4
    for (int j = 0; j < SEGK_T; ++j) {
        float4 a = ldsa[j];   // wave-uniform broadcast, ds_read_b128
        float2 c = ldsc[j];   // ds_read_b64
#pragma unroll
        for (int u = 0; u < QQ_T; ++u) {
            float tt = fmaf(qx[u], a.x, fmaf(qy[u], a.y, fmaf(qz[u], a.z, EXP2_B)));
            float p = __int_as_float((int)tt);   // fast exp2 of the score
            l[u] += p;
            o0[u] = fmaf(p, a.w, o0[u]);
            o1[u] = fmaf(p, c.x, o1[u]);
            o2[u] = fmaf(p, c.y, o2[u]);
        }
    }

    float4* dst = part + (size_t)seg * BN + qbase;
#pragma unroll
    for (int u = 0; u < QQ_T; ++u)
        dst[TPB * u] = make_float4(l[u], o0[u], o1[u], o2[u]);
}

// ---------------------------------------------------------------------------
// Combine partials + residual (plane-major part -> coalesced).
// ---------------------------------------------------------------------------
__global__ __launch_bounds__(256) void combine_kernel(const float4* __restrict__ part,
                                                      const float* __restrict__ x,
                                                      float* __restrict__ out,
                                                      int nseg) {
    int q = blockIdx.x * 256 + threadIdx.x;   // 0 .. BN-1
    float L = 0.0f, O0 = 0.0f, O1 = 0.0f, O2 = 0.0f;
    for (int s = 0; s < nseg; ++s) {
        float4 p = part[(size_t)s * BN + q];
        L  += p.x;
        O0 += p.y;
        O1 += p.z;
        O2 += p.w;
    }
    float inv = 1.0f / L;
    out[q * 3 + 0] = fmaf(O0, inv, x[q * 3 + 0]);
    out[q * 3 + 1] = fmaf(O1, inv, x[q * 3 + 1]);
    out[q * 3 + 2] = fmaf(O2, inv, x[q * 3 + 2]);
}

template <int NSEG_T, int QQ_T>
static void launch_all(const float* x, const float* W, const float* bias,
                       float4* part, float* out, hipStream_t stream) {
    dim3 g(NSEG_T, NN / (TPB * QQ_T), BB);
    attn_fused_kernel<NSEG_T, QQ_T><<<g, TPB, 0, stream>>>(x, W, bias, part);
    combine_kernel<<<BN / 256, 256, 0, stream>>>(part, x, out, NSEG_T);
}

extern "C" void kernel_launch(void* const* d_in, const int* in_sizes, int n_in,
                              void* d_out, int out_size, void* d_ws, size_t ws_size,
                              hipStream_t stream) {
    const float* x    = (const float*)d_in[0];  // (B, N, 3)
    const float* W    = (const float*)d_in[1];  // (9, 3)
    const float* bias = (const float*)d_in[2];  // (9,)
    float* out = (float*)d_out;                 // (B, N, 3)
    float4* part = (float4*)d_ws;

    // Deterministic tier select on constant ws_size (same work every call).
    size_t plane = (size_t)BN * 16;
    if (ws_size >= 64 * plane)      launch_all<64, 8>(x, W, bias, part, out, stream);
    else if (ws_size >= 32 * plane) launch_all<32, 4>(x, W, bias, part, out, stream);  // R4 config
    else                            launch_all<16, 4>(x, W, bias, part, out, stream);
}

// Round 6
// 113.357 us; speedup vs baseline: 1.0934x; 1.0934x over previous
//
#include <hip/hip_runtime.h>
#include <math.h>

// Problem constants (reference: B=4, N=8192, PIXEL_DIM=3).
#define BB   4
#define NN   8192
#define BN   (BB * NN)
#define TPB  256

// Schraudolph exp2: p = bitcast(int(t)), t = s*2^23 + B, B = (127-c)*2^23,
// c = 0.0355 balances max rel err ~+/-3.5%; systematic part cancels in softmax.
#define EXP2_B 1.06505542e9f
// 2^23 * log2(e) / sqrt(3): folds score scale + bit-trick scale.
#define QSCALE (8388608.0f * 1.4426950408889634f / 1.7320508075688772f)

// ---------------------------------------------------------------------------
// Fused QKV + split-K attention partials, key-side reassociation.
// qkv rows (reference view(B,N,3,-1)[...,i], d==3):
//   q_j = row 3j (0,3,6), k_j = 3j+1 (1,4,7), v_j = 3j+2 (2,5,8).
// Reassociation: q.k = (Wk^T q).x_key + q.bk  ->  per-query qt[3] and seed
// Bu = EXP2_B + QSCALE*(q.bk). Inner loop touches only raw x of the key
// (12 B, 4 keys per 3x ds_read_b128, wave-uniform broadcast). Accumulate
// L = sum p and G = sum p*x_key; v is applied once in combine:
//   out = Wv*(G/L) + bv + x  (since v = Wv x + bv).
// Per pair: 3 FMA (dot, seeded Bu) + 1 cvt + 1 add + 3 FMA = 8 VALU ops.
// ---------------------------------------------------------------------------
template <int NSEG_T, int QQ_T>
__global__ __launch_bounds__(TPB) void attn_fused_kernel(const float* __restrict__ x,
                                                         const float* __restrict__ W,
                                                         const float* __restrict__ bias,
                                                         float4* __restrict__ part) {
    constexpr int SEGK_T  = NN / NSEG_T;       // 256 at NSEG=32
    constexpr int QTILE_T = TPB * QQ_T;        // 1024 at QQ=4
    __shared__ float ldsx[SEGK_T * 3];         // raw x of keys, 12 B/key

    const int seg = blockIdx.x;
    const int qt  = blockIdx.y;
    const int b   = blockIdx.z;
    const int t   = threadIdx.x;

    // Uniform weights -> registers (scalar-promoted).
    float Wr[9][3], br[9];
#pragma unroll
    for (int c = 0; c < 9; ++c) {
        Wr[c][0] = W[c * 3 + 0];
        Wr[c][1] = W[c * 3 + 1];
        Wr[c][2] = W[c * 3 + 2];
        br[c] = bias[c];
    }

    // Stage: pure copy of the segment's x rows (SEGK*3 floats, 16B-aligned).
    {
        const float4* src = (const float4*)(x + (size_t)(b * NN + seg * SEGK_T) * 3);
        float4* dst4 = (float4*)ldsx;
        for (int i = t; i < SEGK_T * 3 / 4; i += TPB) dst4[i] = src[i];
    }

    // Per-thread queries: q = Wq x + bq, then qt = QSCALE*Wk^T q and
    // per-query seed Bu = EXP2_B + QSCALE*(q.bk).
    const int qbase = b * NN + qt * QTILE_T + t;
    float qx[QQ_T], qy[QQ_T], qz[QQ_T], Bu[QQ_T];
#pragma unroll
    for (int u = 0; u < QQ_T; ++u) {
        const float* xq = x + (size_t)(qbase + TPB * u) * 3;
        float x0 = xq[0], x1 = xq[1], x2 = xq[2];
        float q0 = fmaf(x0, Wr[0][0], fmaf(x1, Wr[0][1], fmaf(x2, Wr[0][2], br[0])));
        float q1 = fmaf(x0, Wr[3][0], fmaf(x1, Wr[3][1], fmaf(x2, Wr[3][2], br[3])));
        float q2 = fmaf(x0, Wr[6][0], fmaf(x1, Wr[6][1], fmaf(x2, Wr[6][2], br[6])));
        // Wk rows are qkv rows 1,4,7; Wk^T q component i = sum_j Wk[j][i]*q_j.
        qx[u] = QSCALE * fmaf(q0, Wr[1][0], fmaf(q1, Wr[4][0], q2 * Wr[7][0]));
        qy[u] = QSCALE * fmaf(q0, Wr[1][1], fmaf(q1, Wr[4][1], q2 * Wr[7][1]));
        qz[u] = QSCALE * fmaf(q0, Wr[1][2], fmaf(q1, Wr[4][2], q2 * Wr[7][2]));
        Bu[u] = fmaf(QSCALE, fmaf(q0, br[1], fmaf(q1, br[4], q2 * br[7])), EXP2_B);
    }

    __syncthreads();

    float l[QQ_T], g0[QQ_T], g1[QQ_T], g2[QQ_T];
#pragma unroll
    for (int u = 0; u < QQ_T; ++u) { l[u] = 0.f; g0[u] = 0.f; g1[u] = 0.f; g2[u] = 0.f; }

    // 4 keys per group: 3x ds_read_b128 with immediate offsets.
    const float4* lds4 = (const float4*)ldsx;
#pragma unroll 2
    for (int jg = 0; jg < SEGK_T / 4; ++jg) {
        float4 r0 = lds4[jg * 3 + 0];
        float4 r1 = lds4[jg * 3 + 1];
        float4 r2 = lds4[jg * 3 + 2];
        float kx[4] = {r0.x, r0.w, r1.z, r2.y};
        float ky[4] = {r0.y, r1.x, r1.w, r2.z};
        float kz[4] = {r0.z, r1.y, r2.x, r2.w};
#pragma unroll
        for (int kk = 0; kk < 4; ++kk) {
#pragma unroll
            for (int u = 0; u < QQ_T; ++u) {
                float tt = fmaf(qx[u], kx[kk], fmaf(qy[u], ky[kk], fmaf(qz[u], kz[kk], Bu[u])));
                float p = __int_as_float((int)tt);   // fast exp2 of the score
                l[u]  += p;
                g0[u] = fmaf(p, kx[kk], g0[u]);
                g1[u] = fmaf(p, ky[kk], g1[u]);
                g2[u] = fmaf(p, kz[kk], g2[u]);
            }
        }
    }

    float4* dst = part + (size_t)seg * BN + qbase;
#pragma unroll
    for (int u = 0; u < QQ_T; ++u)
        dst[TPB * u] = make_float4(l[u], g0[u], g1[u], g2[u]);
}

// ---------------------------------------------------------------------------
// Combine partials, apply v-projection + residual:
//   out_c = Wv[c] . (G/L) + bv[c] + x_c   (Wv rows = qkv rows 2,5,8).
// ---------------------------------------------------------------------------
__global__ __launch_bounds__(256) void combine_kernel(const float4* __restrict__ part,
                                                      const float* __restrict__ x,
                                                      const float* __restrict__ W,
                                                      const float* __restrict__ bias,
                                                      float* __restrict__ out,
                                                      int nseg) {
    int q = blockIdx.x * 256 + threadIdx.x;   // 0 .. BN-1
    float L = 0.0f, G0 = 0.0f, G1 = 0.0f, G2 = 0.0f;
    for (int s = 0; s < nseg; ++s) {
        float4 p = part[(size_t)s * BN + q];
        L  += p.x;
        G0 += p.y;
        G1 += p.z;
        G2 += p.w;
    }
    float inv = 1.0f / L;
    float a0 = G0 * inv, a1 = G1 * inv, a2 = G2 * inv;
#pragma unroll
    for (int c = 0; c < 3; ++c) {
        int r = 3 * c + 2;  // Wv rows 2,5,8
        float o = fmaf(a0, W[r * 3 + 0], fmaf(a1, W[r * 3 + 1],
                  fmaf(a2, W[r * 3 + 2], bias[r])));
        out[q * 3 + c] = o + x[q * 3 + c];
    }
}

template <int NSEG_T, int QQ_T>
static void launch_all(const float* x, const float* W, const float* bias,
                       float4* part, float* out, hipStream_t stream) {
    dim3 g(NSEG_T, NN / (TPB * QQ_T), BB);
    attn_fused_kernel<NSEG_T, QQ_T><<<g, TPB, 0, stream>>>(x, W, bias, part);
    combine_kernel<<<BN / 256, 256, 0, stream>>>(part, x, W, bias, out, NSEG_T);
}

extern "C" void kernel_launch(void* const* d_in, const int* in_sizes, int n_in,
                              void* d_out, int out_size, void* d_ws, size_t ws_size,
                              hipStream_t stream) {
    const float* x    = (const float*)d_in[0];  // (B, N, 3)
    const float* W    = (const float*)d_in[1];  // (9, 3)
    const float* bias = (const float*)d_in[2];  // (9,)
    float* out = (float*)d_out;                 // (B, N, 3)
    float4* part = (float4*)d_ws;

    // Deterministic tier select on constant ws_size (same work every call).
    size_t plane = (size_t)BN * 16;
    if (ws_size >= 32 * plane)      launch_all<32, 4>(x, W, bias, part, out, stream);
    else if (ws_size >= 16 * plane) launch_all<16, 4>(x, W, bias, part, out, stream);
    else                            launch_all<8, 4>(x, W, bias, part, out, stream);
}